// Round 5
// baseline (429.736 us; speedup 1.0000x reference)
//
#include <hip/hip_runtime.h>
#include <hip/hip_bf16.h>
#include <math.h>

#define B 4
#define H 256
#define W 256
#define HW 65536
#define BHW (B * HW)
#define LSTEPS 10
#define NCH 100
#define NSPLIT 2
#define CPS (NCH / NSPLIT)   // 50 channels per block
#define KS 51
#define KR 25

// ---------------- init: copy source->images[0], broadcast z0->residuals[0], gauss weights
__global__ void init_kernel(const float* __restrict__ src, const float* __restrict__ z0,
                            float* __restrict__ images0, float* __restrict__ res0,
                            float* __restrict__ gw) {
    int tid = blockIdx.x * 256 + threadIdx.x;   // 0 .. B*HW-1
    images0[tid] = src[tid];
    res0[tid] = z0[tid & (HW - 1)];
    if (blockIdx.x == 0 && threadIdx.x == 0) {
        float e[KS];
        float s = 0.f;
        for (int k = 0; k < KS; k++) {
            float x = (float)(k - KR) / 6.0f;
            e[k] = expf(-0.5f * x * x);
            s += e[k];
        }
        for (int k = 0; k < KS; k++) gw[k] = e[k] / s;
    }
}

// ---------------- weight repack: per (step,channel) 32-float record
// [0..8]=w1 z-chan, [9..17]=w1 img-chan, [18..26]=conv2, [27]=bias, [28..31]=0
__global__ void wrepack_kernel(const float* __restrict__ conv1_w, const float* __restrict__ conv1_b,
                               const float* __restrict__ conv2_w, float* __restrict__ wpack) {
    int idx = blockIdx.x * 256 + threadIdx.x;   // 0 .. LSTEPS*NCH-1
    if (idx >= LSTEPS * NCH) return;
    int i = idx / NCH, c = idx % NCH;
    float* dst = wpack + (size_t)idx * 32;
    const float* w1c = conv1_w + (size_t)i * NCH * 18 + c * 18;
    const float* w2c = conv2_w + (size_t)i * NCH * 9 + c * 9;
#pragma unroll
    for (int k = 0; k < 18; k++) dst[k] = w1c[k];
#pragma unroll
    for (int k = 0; k < 9; k++) dst[18 + k] = w2c[k];
    dst[27] = conv1_b[(size_t)i * NCH + c];
    dst[28] = 0.f; dst[29] = 0.f; dst[30] = 0.f; dst[31] = 0.f;
}

// ---------------- fused sobel + S-map resblock, 2-way channel split for occupancy
// grid: 2048 blocks (bit0 = channel half), 256 threads, 1 pixel/thread, 50 ch/block
__global__ __launch_bounds__(256, 8) void grad_smap_kernel(
        const float* __restrict__ z, const float* __restrict__ img,
        const float* __restrict__ wp, __hip_bfloat16* __restrict__ S,
        float* __restrict__ grads_i, float* __restrict__ t) {
    int bid = blockIdx.x;
    int g = bid & 1;                            // channel half
    int tid = (bid >> 1) * 256 + threadIdx.x;   // pixel id 0 .. B*HW-1
    int b = tid >> 16;
    int p = tid & (HW - 1);
    int y = p >> 8, x = p & 255;
    const float* zp = z + (b << 16);
    const float* ip = img + (b << 16);

    // clamped-index loads; ri = raw img (Sobel edge-pad), pz/pi = zero-padded conv inputs
    float ri[9], pz[9], pi[9];
#pragma unroll
    for (int dy = -1; dy <= 1; dy++) {
#pragma unroll
        for (int dx = -1; dx <= 1; dx++) {
            int yy = y + dy, xx = x + dx;
            bool ok = ((unsigned)yy < (unsigned)H) && ((unsigned)xx < (unsigned)W);
            int yc = min(max(yy, 0), H - 1);
            int xc = min(max(xx, 0), W - 1);
            int k = (dy + 1) * 3 + (dx + 1);
            float vz = zp[yc * W + xc], vi = ip[yc * W + xc];
            ri[k] = vi;
            pz[k] = ok ? vz : 0.f;
            pi[k] = ok ? vi : 0.f;
        }
    }

    if (g == 0) {   // block-uniform: only half 0 writes grads / t
        float gx = ((ri[2] + 2.f * ri[5] + ri[8]) - (ri[0] + 2.f * ri[3] + ri[6])) * 0.125f;
        float gy = ((ri[6] + 2.f * ri[7] + ri[8]) - (ri[0] + 2.f * ri[1] + ri[2])) * 0.125f;
        grads_i[(b * 2 + 0) * HW + p] = gx;
        grads_i[(b * 2 + 1) * HW + p] = gy;
        float zc = pz[4];                       // center always in-bounds
        t[(b * 2 + 0) * HW + p] = -zc * gx;
        t[(b * 2 + 1) * HW + p] = -zc * gy;
    }

    // S-map partial over this channel half
    float s[9];
#pragma unroll
    for (int q = 0; q < 9; q++) s[q] = 0.f;

    const float* wpg = wp + g * CPS * 32;
#pragma unroll 2
    for (int c = 0; c < CPS; c++) {
        const float* wc = wpg + c * 32;          // uniform -> s_load_dwordx16 x2
        float hz = wc[27];
        float hi = 0.f;
#pragma unroll
        for (int k = 0; k < 9; k++) {
            hz = fmaf(wc[k], pz[k], hz);
            hi = fmaf(wc[9 + k], pi[k], hi);
        }
        float a = hz + hi;
        float h = fmaxf(a, 0.01f * a);           // leaky relu
#pragma unroll
        for (int q = 0; q < 9; q++) s[q] = fmaf(wc[18 + q], h, s[q]);
    }

    // interleaved halves: S[(q*BHW + pixel)*2 + g]
#pragma unroll
    for (int q = 0; q < 9; q++)
        S[(((size_t)q * BHW + tid) << 1) + g] = __float2bfloat16(s[q]);
}

// ---------------- vertical 51-tap blur (zero pad), 2D tiled
// grid: (B*2) * (W/32) * (H/32) = 512 blocks, 256 threads; 32x32 outputs per block
#define VBC 32
#define VRT 32
__global__ void vblur_kernel(const float* __restrict__ t, const float* __restrict__ gw,
                             float* __restrict__ t2) {
    int bid = blockIdx.x;
    int rt = bid & 7;            // H/VRT
    int ct = (bid >> 3) & 7;     // W/VBC
    int bc = bid >> 6;           // b*2+ch
    int row0 = rt * VRT, col0 = ct * VBC;
    __shared__ float s[(VRT + 2 * KR) * VBC];    // 82*32 floats
    const float* src = t + bc * HW + col0;
    for (int idx = threadIdx.x; idx < (VRT + 2 * KR) * VBC; idx += 256) {
        int r = idx >> 5, c = idx & 31;
        int row = row0 + r - KR;
        s[idx] = ((unsigned)row < (unsigned)H) ? src[row * W + c] : 0.f;
    }
    __syncthreads();
    int c = threadIdx.x & 31;
    int rbase = (threadIdx.x >> 5) * 4;          // 8 groups of 4 rows
    float* dst = t2 + bc * HW + col0;
#pragma unroll
    for (int j = 0; j < 4; j++) {
        int row = rbase + j;
        float acc = 0.f;
#pragma unroll
        for (int k = 0; k < KS; k++) acc += gw[k] * s[(row + k) * VBC + c];
        dst[(row0 + row) * W + c] = acc;
    }
}

// ---------------- horizontal 51-tap blur + fields write + S-gather (conv2 finish) + deform
// grid: B*H blocks, 256 threads (one row per block, one pixel per thread)
__global__ void hblur_deform_kernel(const float* __restrict__ t2, const float* __restrict__ gw,
                                    float* __restrict__ fields_i,
                                    const float* __restrict__ img, const float* __restrict__ z,
                                    const __hip_bfloat16* __restrict__ S,
                                    float* __restrict__ res_next, float* __restrict__ img_next) {
    int b = blockIdx.x >> 8;
    int row = blockIdx.x & 255;
    __shared__ float s0[W + 2 * KR], s1[W + 2 * KR];
    const float* r0 = t2 + (b * 2 + 0) * HW + row * W;
    const float* r1 = t2 + (b * 2 + 1) * HW + row * W;
    for (int idx = threadIdx.x; idx < W + 2 * KR; idx += 256) {
        int xx = idx - KR;
        bool ok = (xx >= 0 && xx < W);
        s0[idx] = ok ? r0[xx] : 0.f;
        s1[idx] = ok ? r1[xx] : 0.f;
    }
    __syncthreads();
    int x = threadIdx.x;
    float a0 = 0.f, a1 = 0.f;
#pragma unroll
    for (int k = 0; k < KS; k++) {
        float wk = gw[k];
        a0 += wk * s0[x + k];
        a1 += wk * s1[x + k];
    }
    int p = row * W + x;
    int tid = (b << 16) + p;
    float2* fdst = (float2*)(fields_i + (size_t)tid * 2);
    *fdst = make_float2(a0, a1);

    // conv2 finish: out[y,x] = sum_t (S0+S1)[y-1+ty, x-1+tx], zero outside image
    float f = 0.f;
#pragma unroll
    for (int q = 0; q < 9; q++) {
        int yy = row - 1 + q / 3;
        int xx = x - 1 + q % 3;
        if (((unsigned)yy < (unsigned)H) && ((unsigned)xx < (unsigned)W)) {
            const __hip_bfloat16* sp = S + (((size_t)q * BHW + (b << 16) + yy * W + xx) << 1);
            f += __bfloat162float(sp[0]) + __bfloat162float(sp[1]);
        }
    }
    float zn = z[tid] + f / 10.0f;
    res_next[tid] = zn;

    // bilinear deform
    float sx = (float)x - a0 / 10.0f;
    float sy = (float)row - a1 / 10.0f;
    float x0f = floorf(sx), y0f = floorf(sy);
    float wx = sx - x0f, wy = sy - y0f;
    int ix0 = min(max((int)x0f, 0), W - 1);
    int ix1 = min(max((int)x0f + 1, 0), W - 1);
    int iy0 = min(max((int)y0f, 0), H - 1);
    int iy1 = min(max((int)y0f + 1, 0), H - 1);
    const float* im = img + (b << 16);
    float Ia = im[iy0 * W + ix0], Ib = im[iy0 * W + ix1];
    float Ic = im[iy1 * W + ix0], Id = im[iy1 * W + ix1];
    float out = (1.f - wx) * (1.f - wy) * Ia + wx * (1.f - wy) * Ib
              + (1.f - wx) * wy * Ic + wx * wy * Id;
    img_next[tid] = out + zn * 0.001f;   // + z_next * MU^2 / L
}

extern "C" void kernel_launch(void* const* d_in, const int* in_sizes, int n_in,
                              void* d_out, int out_size, void* d_ws, size_t ws_size,
                              hipStream_t stream) {
    const float* source  = (const float*)d_in[0];
    const float* z0      = (const float*)d_in[1];
    const float* conv1_w = (const float*)d_in[2];
    const float* conv1_b = (const float*)d_in[3];
    const float* conv2_w = (const float*)d_in[4];

    float* out = (float*)d_out;
    float* images    = out;                              // [11][B][HW]
    float* fields    = images + (size_t)11 * B * HW;     // [10][B][HW][2]
    float* residuals = fields + (size_t)10 * B * HW * 2; // [11][B][HW]
    float* grads     = residuals + (size_t)11 * B * HW;  // [10][B][2][HW]

    float* ws = (float*)d_ws;
    float* t  = ws;                           // [B][2][HW] f32
    float* t2 = t + (size_t)B * 2 * HW;       // [B][2][HW] f32
    __hip_bfloat16* S = (__hip_bfloat16*)(t2 + (size_t)B * 2 * HW);  // [9][BHW][2] bf16
    float* gw = (float*)(S + (size_t)9 * BHW * 2);                   // [51]
    float* wpack = gw + 64;                   // [LSTEPS*NCH][32]

    init_kernel<<<B * HW / 256, 256, 0, stream>>>(source, z0, images, residuals, gw);
    wrepack_kernel<<<(LSTEPS * NCH + 255) / 256, 256, 0, stream>>>(conv1_w, conv1_b, conv2_w, wpack);

    for (int i = 0; i < LSTEPS; i++) {
        const float* img_i = images + (size_t)i * B * HW;
        const float* z_i   = residuals + (size_t)i * B * HW;
        float* fields_i    = fields + (size_t)i * B * HW * 2;

        grad_smap_kernel<<<B * HW / 256 * NSPLIT, 256, 0, stream>>>(z_i, img_i,
                wpack + (size_t)i * NCH * 32, S,
                grads + (size_t)i * B * 2 * HW, t);
        vblur_kernel<<<B * 2 * (W / VBC) * (H / VRT), 256, 0, stream>>>(t, gw, t2);
        hblur_deform_kernel<<<B * H, 256, 0, stream>>>(t2, gw, fields_i,
                img_i, z_i, S,
                residuals + (size_t)(i + 1) * B * HW, images + (size_t)(i + 1) * B * HW);
    }
}

// Round 7
// 387.909 us; speedup vs baseline: 1.1078x; 1.1078x over previous
//
#include <hip/hip_runtime.h>
#include <hip/hip_bf16.h>
#include <math.h>

#define B 4
#define H 256
#define W 256
#define HW 65536
#define BHW (B * HW)
#define LSTEPS 10
#define NCH 100
#define NPAIR (NCH / 2)
#define KS 51
#define KR 25

typedef __fp16 h2 __attribute__((ext_vector_type(2)));

#if __has_builtin(__builtin_amdgcn_fdot2)
#define FDOT2(a, b, c) __builtin_amdgcn_fdot2((a), (b), (c), false)
#else
static __device__ __forceinline__ float FDOT2(h2 a, h2 b, float c) {
    return (float)a.x * (float)b.x + (float)a.y * (float)b.y + c;
}
#endif

static __device__ __forceinline__ h2 pack_f16(float a, float b) {
#if __has_builtin(__builtin_amdgcn_cvt_pkrtz)
    return __builtin_amdgcn_cvt_pkrtz(a, b);
#else
    h2 r; r.x = (__fp16)a; r.y = (__fp16)b; return r;
#endif
}

// ---------------- init: images[0]/residuals[0] + gauss weights + f16 weight repack
// per channel-PAIR 32-dword record:
// h2[0..8]  = (w1z, w1i) taps, channel A
// h2[9..17] = (w1z, w1i) taps, channel B
// h2[18..26]= (v2_A, v2_B) taps
// f32[27] = biasA, f32[28] = biasB, [29..31] pad
__global__ void init_kernel(const float* __restrict__ src, const float* __restrict__ z0,
                            const float* __restrict__ conv1_w, const float* __restrict__ conv1_b,
                            const float* __restrict__ conv2_w,
                            float* __restrict__ images0, float* __restrict__ res0,
                            float* __restrict__ gw, float* __restrict__ wpack) {
    int tid = blockIdx.x * 256 + threadIdx.x;   // 0 .. BHW-1
    images0[tid] = src[tid];
    res0[tid] = z0[tid & (HW - 1)];
    if (blockIdx.x == 0 && threadIdx.x == 0) {
        float e[KS];
        float s = 0.f;
        for (int k = 0; k < KS; k++) {
            float x = (float)(k - KR) / 6.0f;
            e[k] = expf(-0.5f * x * x);
            s += e[k];
        }
        for (int k = 0; k < KS; k++) gw[k] = e[k] / s;
    }
    int pidx = tid - 256;                       // blocks 1..2 cover 0..511
    if (pidx >= 0 && pidx < LSTEPS * NPAIR) {
        int i = pidx / NPAIR, cp = pidx % NPAIR;
        int cA = 2 * cp, cB = 2 * cp + 1;
        const float* w1A = conv1_w + ((size_t)i * NCH + cA) * 18;
        const float* w1B = conv1_w + ((size_t)i * NCH + cB) * 18;
        const float* w2A = conv2_w + ((size_t)i * NCH + cA) * 9;
        const float* w2B = conv2_w + ((size_t)i * NCH + cB) * 9;
        float* dst = wpack + (size_t)pidx * 32;
        h2* d2 = (h2*)dst;
#pragma unroll
        for (int k = 0; k < 9; k++) {
            h2 a; a.x = (__fp16)w1A[k]; a.y = (__fp16)w1A[9 + k]; d2[k] = a;
            h2 bb; bb.x = (__fp16)w1B[k]; bb.y = (__fp16)w1B[9 + k]; d2[9 + k] = bb;
            h2 v; v.x = (__fp16)w2A[k]; v.y = (__fp16)w2B[k]; d2[18 + k] = v;
        }
        dst[27] = conv1_b[(size_t)i * NCH + cA];
        dst[28] = conv1_b[(size_t)i * NCH + cB];
        dst[29] = 0.f; dst[30] = 0.f; dst[31] = 0.f;
    }
}

// ---------------- fused sobel + S-map resblock via packed-f16 dot2
// grid: BHW/256 = 1024 blocks, 256 threads, 1 pixel/thread, all 100 channels
__global__ __launch_bounds__(256, 4) void grad_smap_kernel(
        const float* __restrict__ z, const float* __restrict__ img,
        const float* __restrict__ wp, __hip_bfloat16* __restrict__ S,
        float* __restrict__ grads_i, float* __restrict__ t) {
    int tid = blockIdx.x * 256 + threadIdx.x;   // 0 .. BHW-1
    int b = tid >> 16;
    int p = tid & (HW - 1);
    int y = p >> 8, x = p & 255;
    const float* zp = z + (b << 16);
    const float* ip = img + (b << 16);

    // clamped loads; ri = raw img (Sobel edge-pad); pzi = packed (z,img) zero-padded
    float ri[9];
    h2 pzi[9];
    float zc = 0.f;
#pragma unroll
    for (int dy = -1; dy <= 1; dy++) {
#pragma unroll
        for (int dx = -1; dx <= 1; dx++) {
            int yy = y + dy, xx = x + dx;
            bool ok = ((unsigned)yy < (unsigned)H) && ((unsigned)xx < (unsigned)W);
            int yc = min(max(yy, 0), H - 1);
            int xc = min(max(xx, 0), W - 1);
            int k = (dy + 1) * 3 + (dx + 1);
            float vz = zp[yc * W + xc], vi = ip[yc * W + xc];
            ri[k] = vi;
            float az = ok ? vz : 0.f, ai = ok ? vi : 0.f;
            if (k == 4) zc = az;
            pzi[k] = pack_f16(az, ai);
        }
    }

    // Sobel on edge-clamped img values
    float gx = ((ri[2] + 2.f * ri[5] + ri[8]) - (ri[0] + 2.f * ri[3] + ri[6])) * 0.125f;
    float gy = ((ri[6] + 2.f * ri[7] + ri[8]) - (ri[0] + 2.f * ri[1] + ri[2])) * 0.125f;
    grads_i[(b * 2 + 0) * HW + p] = gx;
    grads_i[(b * 2 + 1) * HW + p] = gy;
    t[(b * 2 + 0) * HW + p] = -zc * gx;
    t[(b * 2 + 1) * HW + p] = -zc * gy;

    // S-map: S_q[p] = sum_c v2[c][q] * leaky(conv1_c(p)), channel pairs via dot2
    float s[9];
#pragma unroll
    for (int q = 0; q < 9; q++) s[q] = 0.f;

#pragma unroll 2
    for (int cp = 0; cp < NPAIR; cp++) {
        const float* wc = wp + cp * 32;          // uniform -> scalar loads
        const h2* wc2 = (const h2*)wc;
        float hA = wc[27];
        float hB = wc[28];
#pragma unroll
        for (int k = 0; k < 9; k++) {
            hA = FDOT2(wc2[k], pzi[k], hA);
            hB = FDOT2(wc2[9 + k], pzi[k], hB);
        }
        float lA = fmaxf(hA, 0.01f * hA);        // leaky relu
        float lB = fmaxf(hB, 0.01f * hB);
        h2 hh = pack_f16(lA, lB);
#pragma unroll
        for (int q = 0; q < 9; q++) s[q] = FDOT2(wc2[18 + q], hh, s[q]);
    }

#pragma unroll
    for (int q = 0; q < 9; q++)
        S[(size_t)q * BHW + tid] = __float2bfloat16(s[q]);
}

// ---------------- vertical 51-tap blur (zero pad), 2D tiled
// grid: (B*2) * (W/32) * (H/32) = 512 blocks, 256 threads; 32x32 outputs per block
#define VBC 32
#define VRT 32
__global__ void vblur_kernel(const float* __restrict__ t, const float* __restrict__ gw,
                             float* __restrict__ t2) {
    int bid = blockIdx.x;
    int rt = bid & 7;            // H/VRT
    int ct = (bid >> 3) & 7;     // W/VBC
    int bc = bid >> 6;           // b*2+ch
    int row0 = rt * VRT, col0 = ct * VBC;
    __shared__ float s[(VRT + 2 * KR) * VBC];    // 82*32 floats
    const float* src = t + bc * HW + col0;
    for (int idx = threadIdx.x; idx < (VRT + 2 * KR) * VBC; idx += 256) {
        int r = idx >> 5, c = idx & 31;
        int row = row0 + r - KR;
        s[idx] = ((unsigned)row < (unsigned)H) ? src[row * W + c] : 0.f;
    }
    __syncthreads();
    int c = threadIdx.x & 31;
    int rbase = (threadIdx.x >> 5) * 4;          // 8 groups of 4 rows
    float* dst = t2 + bc * HW + col0;
#pragma unroll
    for (int j = 0; j < 4; j++) {
        int row = rbase + j;
        float acc = 0.f;
#pragma unroll
        for (int k = 0; k < KS; k++) acc += gw[k] * s[(row + k) * VBC + c];
        dst[(row0 + row) * W + c] = acc;
    }
}

// ---------------- horizontal 51-tap blur + fields write + S-gather (conv2 finish) + deform
// grid: B*H blocks, 256 threads (one row per block, one pixel per thread)
__global__ void hblur_deform_kernel(const float* __restrict__ t2, const float* __restrict__ gw,
                                    float* __restrict__ fields_i,
                                    const float* __restrict__ img, const float* __restrict__ z,
                                    const __hip_bfloat16* __restrict__ S,
                                    float* __restrict__ res_next, float* __restrict__ img_next) {
    int b = blockIdx.x >> 8;
    int row = blockIdx.x & 255;
    __shared__ float s0[W + 2 * KR], s1[W + 2 * KR];
    const float* r0 = t2 + (b * 2 + 0) * HW + row * W;
    const float* r1 = t2 + (b * 2 + 1) * HW + row * W;
    for (int idx = threadIdx.x; idx < W + 2 * KR; idx += 256) {
        int xx = idx - KR;
        bool ok = (xx >= 0 && xx < W);
        s0[idx] = ok ? r0[xx] : 0.f;
        s1[idx] = ok ? r1[xx] : 0.f;
    }
    __syncthreads();
    int x = threadIdx.x;
    float a0 = 0.f, a1 = 0.f;
#pragma unroll
    for (int k = 0; k < KS; k++) {
        float wk = gw[k];
        a0 += wk * s0[x + k];
        a1 += wk * s1[x + k];
    }
    int p = row * W + x;
    int tid = (b << 16) + p;
    float2* fdst = (float2*)(fields_i + (size_t)tid * 2);
    *fdst = make_float2(a0, a1);

    // conv2 finish: out[y,x] = sum_q S_q[y-1+qy, x-1+qx], S == 0 outside image
    float f = 0.f;
#pragma unroll
    for (int q = 0; q < 9; q++) {
        int yy = row - 1 + q / 3;
        int xx = x - 1 + q % 3;
        if (((unsigned)yy < (unsigned)H) && ((unsigned)xx < (unsigned)W))
            f += __bfloat162float(S[(size_t)q * BHW + (b << 16) + yy * W + xx]);
    }
    float zn = z[tid] + f / 10.0f;
    res_next[tid] = zn;

    // bilinear deform
    float sx = (float)x - a0 / 10.0f;
    float sy = (float)row - a1 / 10.0f;
    float x0f = floorf(sx), y0f = floorf(sy);
    float wx = sx - x0f, wy = sy - y0f;
    int ix0 = min(max((int)x0f, 0), W - 1);
    int ix1 = min(max((int)x0f + 1, 0), W - 1);
    int iy0 = min(max((int)y0f, 0), H - 1);
    int iy1 = min(max((int)y0f + 1, 0), H - 1);
    const float* im = img + (b << 16);
    float Ia = im[iy0 * W + ix0], Ib = im[iy0 * W + ix1];
    float Ic = im[iy1 * W + ix0], Id = im[iy1 * W + ix1];
    float out = (1.f - wx) * (1.f - wy) * Ia + wx * (1.f - wy) * Ib
              + (1.f - wx) * wy * Ic + wx * wy * Id;
    img_next[tid] = out + zn * 0.001f;   // + z_next * MU^2 / L
}

extern "C" void kernel_launch(void* const* d_in, const int* in_sizes, int n_in,
                              void* d_out, int out_size, void* d_ws, size_t ws_size,
                              hipStream_t stream) {
    const float* source  = (const float*)d_in[0];
    const float* z0      = (const float*)d_in[1];
    const float* conv1_w = (const float*)d_in[2];
    const float* conv1_b = (const float*)d_in[3];
    const float* conv2_w = (const float*)d_in[4];

    float* out = (float*)d_out;
    float* images    = out;                              // [11][B][HW]
    float* fields    = images + (size_t)11 * B * HW;     // [10][B][HW][2]
    float* residuals = fields + (size_t)10 * B * HW * 2; // [11][B][HW]
    float* grads     = residuals + (size_t)11 * B * HW;  // [10][B][2][HW]

    float* ws = (float*)d_ws;
    float* t  = ws;                           // [B][2][HW] f32
    float* t2 = t + (size_t)B * 2 * HW;       // [B][2][HW] f32
    __hip_bfloat16* S = (__hip_bfloat16*)(t2 + (size_t)B * 2 * HW);  // [9][BHW] bf16
    float* gw = (float*)(S + (size_t)9 * BHW);                       // [64]
    float* wpack = gw + 64;                   // [LSTEPS*NPAIR][32]

    init_kernel<<<BHW / 256, 256, 0, stream>>>(source, z0, conv1_w, conv1_b, conv2_w,
                                               images, residuals, gw, wpack);

    for (int i = 0; i < LSTEPS; i++) {
        const float* img_i = images + (size_t)i * B * HW;
        const float* z_i   = residuals + (size_t)i * B * HW;
        float* fields_i    = fields + (size_t)i * B * HW * 2;

        grad_smap_kernel<<<BHW / 256, 256, 0, stream>>>(z_i, img_i,
                wpack + (size_t)i * NPAIR * 32, S,
                grads + (size_t)i * B * 2 * HW, t);
        vblur_kernel<<<B * 2 * (W / VBC) * (H / VRT), 256, 0, stream>>>(t, gw, t2);
        hblur_deform_kernel<<<B * H, 256, 0, stream>>>(t2, gw, fields_i,
                img_i, z_i, S,
                residuals + (size_t)(i + 1) * B * HW, images + (size_t)(i + 1) * B * HW);
    }
}

// Round 8
// 375.679 us; speedup vs baseline: 1.1439x; 1.0326x over previous
//
#include <hip/hip_runtime.h>
#include <hip/hip_bf16.h>
#include <math.h>

#define B 4
#define H 256
#define W 256
#define HW 65536
#define BHW (B * HW)
#define LSTEPS 10
#define NCH 100
#define NPAIR (NCH / 2)
#define KS 51
#define KR 25

typedef __fp16 h2 __attribute__((ext_vector_type(2)));

#if __has_builtin(__builtin_amdgcn_fdot2)
#define FDOT2(a, b, c) __builtin_amdgcn_fdot2((a), (b), (c), false)
#else
static __device__ __forceinline__ float FDOT2(h2 a, h2 b, float c) {
    return (float)a.x * (float)b.x + (float)a.y * (float)b.y + c;
}
#endif

static __device__ __forceinline__ h2 pack_f16(float a, float b) {
#if __has_builtin(__builtin_amdgcn_cvt_pkrtz)
    return __builtin_amdgcn_cvt_pkrtz(a, b);
#else
    h2 r; r.x = (__fp16)a; r.y = (__fp16)b; return r;
#endif
}

// ---------------- init: images[0]/residuals[0] + gauss weights + f16 weight repack
// per channel-PAIR 32-dword record:
// h2[0..8]  = (w1z, w1i) taps, channel A
// h2[9..17] = (w1z, w1i) taps, channel B
// h2[18..26]= (v2_A, v2_B) taps
// f32[27] = biasA, f32[28] = biasB, [29..31] pad
__global__ void init_kernel(const float* __restrict__ src, const float* __restrict__ z0,
                            const float* __restrict__ conv1_w, const float* __restrict__ conv1_b,
                            const float* __restrict__ conv2_w,
                            float* __restrict__ images0, float* __restrict__ res0,
                            float* __restrict__ gw, float* __restrict__ wpack) {
    int tid = blockIdx.x * 256 + threadIdx.x;   // 0 .. BHW-1
    images0[tid] = src[tid];
    res0[tid] = z0[tid & (HW - 1)];
    if (blockIdx.x == 0 && threadIdx.x == 0) {
        float e[KS];
        float s = 0.f;
        for (int k = 0; k < KS; k++) {
            float x = (float)(k - KR) / 6.0f;
            e[k] = expf(-0.5f * x * x);
            s += e[k];
        }
        for (int k = 0; k < KS; k++) gw[k] = e[k] / s;
    }
    int pidx = tid - 256;                       // blocks 1..2 cover 0..511
    if (pidx >= 0 && pidx < LSTEPS * NPAIR) {
        int i = pidx / NPAIR, cp = pidx % NPAIR;
        int cA = 2 * cp, cB = 2 * cp + 1;
        const float* w1A = conv1_w + ((size_t)i * NCH + cA) * 18;
        const float* w1B = conv1_w + ((size_t)i * NCH + cB) * 18;
        const float* w2A = conv2_w + ((size_t)i * NCH + cA) * 9;
        const float* w2B = conv2_w + ((size_t)i * NCH + cB) * 9;
        float* dst = wpack + (size_t)pidx * 32;
        h2* d2 = (h2*)dst;
#pragma unroll
        for (int k = 0; k < 9; k++) {
            h2 a; a.x = (__fp16)w1A[k]; a.y = (__fp16)w1A[9 + k]; d2[k] = a;
            h2 bb; bb.x = (__fp16)w1B[k]; bb.y = (__fp16)w1B[9 + k]; d2[9 + k] = bb;
            h2 v; v.x = (__fp16)w2A[k]; v.y = (__fp16)w2B[k]; d2[18 + k] = v;
        }
        dst[27] = conv1_b[(size_t)i * NCH + cA];
        dst[28] = conv1_b[(size_t)i * NCH + cB];
        dst[29] = 0.f; dst[30] = 0.f; dst[31] = 0.f;
    }
}

// ---------------- fused sobel + S-map resblock; weights staged in LDS (VGPR-delivered)
// grid: BHW/256 = 1024 blocks, 256 threads, 1 pixel/thread, all 100 channels
__global__ __launch_bounds__(256, 4) void grad_smap_kernel(
        const float* __restrict__ z, const float* __restrict__ img,
        const float* __restrict__ wp, __hip_bfloat16* __restrict__ S,
        float* __restrict__ grads_i, float* __restrict__ t) {
    __shared__ float4 wl[NPAIR * 8];             // 6400 B: this step's weight pack
    for (int j = threadIdx.x; j < NPAIR * 8; j += 256)
        wl[j] = ((const float4*)wp)[j];

    int tid = blockIdx.x * 256 + threadIdx.x;   // 0 .. BHW-1
    int b = tid >> 16;
    int p = tid & (HW - 1);
    int y = p >> 8, x = p & 255;
    const float* zp = z + (b << 16);
    const float* ip = img + (b << 16);

    // clamped loads; ri = raw img (Sobel edge-pad); pzi = packed (z,img) zero-padded
    float ri[9];
    h2 pzi[9];
    float zc = 0.f;
#pragma unroll
    for (int dy = -1; dy <= 1; dy++) {
#pragma unroll
        for (int dx = -1; dx <= 1; dx++) {
            int yy = y + dy, xx = x + dx;
            bool ok = ((unsigned)yy < (unsigned)H) && ((unsigned)xx < (unsigned)W);
            int yc = min(max(yy, 0), H - 1);
            int xc = min(max(xx, 0), W - 1);
            int k = (dy + 1) * 3 + (dx + 1);
            float vz = zp[yc * W + xc], vi = ip[yc * W + xc];
            ri[k] = vi;
            float az = ok ? vz : 0.f, ai = ok ? vi : 0.f;
            if (k == 4) zc = az;
            pzi[k] = pack_f16(az, ai);
        }
    }

    // Sobel on edge-clamped img values
    float gx = ((ri[2] + 2.f * ri[5] + ri[8]) - (ri[0] + 2.f * ri[3] + ri[6])) * 0.125f;
    float gy = ((ri[6] + 2.f * ri[7] + ri[8]) - (ri[0] + 2.f * ri[1] + ri[2])) * 0.125f;
    grads_i[(b * 2 + 0) * HW + p] = gx;
    grads_i[(b * 2 + 1) * HW + p] = gy;
    t[(b * 2 + 0) * HW + p] = -zc * gx;
    t[(b * 2 + 1) * HW + p] = -zc * gy;

    __syncthreads();                             // weights staged

    // S-map: S_q[p] = sum_c v2[c][q] * leaky(conv1_c(p)), channel pairs via dot2
    float s[9];
#pragma unroll
    for (int q = 0; q < 9; q++) s[q] = 0.f;

#pragma unroll 2
    for (int cp = 0; cp < NPAIR; cp++) {
        float4 wv[8];                            // VGPR copy (static-indexed)
#pragma unroll
        for (int j = 0; j < 8; j++) wv[j] = wl[cp * 8 + j];
        const h2* wc2 = (const h2*)wv;
        const float* wf = (const float*)wv;
        float hA = wf[27];
        float hB = wf[28];
#pragma unroll
        for (int k = 0; k < 9; k++) {
            hA = FDOT2(wc2[k], pzi[k], hA);
            hB = FDOT2(wc2[9 + k], pzi[k], hB);
        }
        float lA = fmaxf(hA, 0.01f * hA);        // leaky relu
        float lB = fmaxf(hB, 0.01f * hB);
        h2 hh = pack_f16(lA, lB);
#pragma unroll
        for (int q = 0; q < 9; q++) s[q] = FDOT2(wc2[18 + q], hh, s[q]);
    }

#pragma unroll
    for (int q = 0; q < 9; q++)
        S[(size_t)q * BHW + tid] = __float2bfloat16(s[q]);
}

// ---------------- vertical 51-tap blur (zero pad), 2D tiled
// grid: (B*2) * (W/32) * (H/32) = 512 blocks, 256 threads; 32x32 outputs per block
#define VBC 32
#define VRT 32
__global__ void vblur_kernel(const float* __restrict__ t, const float* __restrict__ gw,
                             float* __restrict__ t2) {
    int bid = blockIdx.x;
    int rt = bid & 7;            // H/VRT
    int ct = (bid >> 3) & 7;     // W/VBC
    int bc = bid >> 6;           // b*2+ch
    int row0 = rt * VRT, col0 = ct * VBC;
    __shared__ float s[(VRT + 2 * KR) * VBC];    // 82*32 floats
    const float* src = t + bc * HW + col0;
    for (int idx = threadIdx.x; idx < (VRT + 2 * KR) * VBC; idx += 256) {
        int r = idx >> 5, c = idx & 31;
        int row = row0 + r - KR;
        s[idx] = ((unsigned)row < (unsigned)H) ? src[row * W + c] : 0.f;
    }
    __syncthreads();
    int c = threadIdx.x & 31;
    int rbase = (threadIdx.x >> 5) * 4;          // 8 groups of 4 rows
    float* dst = t2 + bc * HW + col0;
#pragma unroll
    for (int j = 0; j < 4; j++) {
        int row = rbase + j;
        float acc = 0.f;
#pragma unroll
        for (int k = 0; k < KS; k++) acc += gw[k] * s[(row + k) * VBC + c];
        dst[(row0 + row) * W + c] = acc;
    }
}

// ---------------- horizontal 51-tap blur + fields write + S-gather (conv2 finish) + deform
// grid: B*H blocks, 256 threads (one row per block, one pixel per thread)
__global__ void hblur_deform_kernel(const float* __restrict__ t2, const float* __restrict__ gw,
                                    float* __restrict__ fields_i,
                                    const float* __restrict__ img, const float* __restrict__ z,
                                    const __hip_bfloat16* __restrict__ S,
                                    float* __restrict__ res_next, float* __restrict__ img_next) {
    int b = blockIdx.x >> 8;
    int row = blockIdx.x & 255;
    __shared__ float s0[W + 2 * KR], s1[W + 2 * KR];
    const float* r0 = t2 + (b * 2 + 0) * HW + row * W;
    const float* r1 = t2 + (b * 2 + 1) * HW + row * W;
    for (int idx = threadIdx.x; idx < W + 2 * KR; idx += 256) {
        int xx = idx - KR;
        bool ok = (xx >= 0 && xx < W);
        s0[idx] = ok ? r0[xx] : 0.f;
        s1[idx] = ok ? r1[xx] : 0.f;
    }
    __syncthreads();
    int x = threadIdx.x;
    float a0 = 0.f, a1 = 0.f;
#pragma unroll
    for (int k = 0; k < KS; k++) {
        float wk = gw[k];
        a0 += wk * s0[x + k];
        a1 += wk * s1[x + k];
    }
    int p = row * W + x;
    int tid = (b << 16) + p;
    float2* fdst = (float2*)(fields_i + (size_t)tid * 2);
    *fdst = make_float2(a0, a1);

    // conv2 finish: out[y,x] = sum_q S_q[y-1+qy, x-1+qx], S == 0 outside image
    float f = 0.f;
#pragma unroll
    for (int q = 0; q < 9; q++) {
        int yy = row - 1 + q / 3;
        int xx = x - 1 + q % 3;
        if (((unsigned)yy < (unsigned)H) && ((unsigned)xx < (unsigned)W))
            f += __bfloat162float(S[(size_t)q * BHW + (b << 16) + yy * W + xx]);
    }
    float zn = z[tid] + f / 10.0f;
    res_next[tid] = zn;

    // bilinear deform
    float sx = (float)x - a0 / 10.0f;
    float sy = (float)row - a1 / 10.0f;
    float x0f = floorf(sx), y0f = floorf(sy);
    float wx = sx - x0f, wy = sy - y0f;
    int ix0 = min(max((int)x0f, 0), W - 1);
    int ix1 = min(max((int)x0f + 1, 0), W - 1);
    int iy0 = min(max((int)y0f, 0), H - 1);
    int iy1 = min(max((int)y0f + 1, 0), H - 1);
    const float* im = img + (b << 16);
    float Ia = im[iy0 * W + ix0], Ib = im[iy0 * W + ix1];
    float Ic = im[iy1 * W + ix0], Id = im[iy1 * W + ix1];
    float out = (1.f - wx) * (1.f - wy) * Ia + wx * (1.f - wy) * Ib
              + (1.f - wx) * wy * Ic + wx * wy * Id;
    img_next[tid] = out + zn * 0.001f;   // + z_next * MU^2 / L
}

extern "C" void kernel_launch(void* const* d_in, const int* in_sizes, int n_in,
                              void* d_out, int out_size, void* d_ws, size_t ws_size,
                              hipStream_t stream) {
    const float* source  = (const float*)d_in[0];
    const float* z0      = (const float*)d_in[1];
    const float* conv1_w = (const float*)d_in[2];
    const float* conv1_b = (const float*)d_in[3];
    const float* conv2_w = (const float*)d_in[4];

    float* out = (float*)d_out;
    float* images    = out;                              // [11][B][HW]
    float* fields    = images + (size_t)11 * B * HW;     // [10][B][HW][2]
    float* residuals = fields + (size_t)10 * B * HW * 2; // [11][B][HW]
    float* grads     = residuals + (size_t)11 * B * HW;  // [10][B][2][HW]

    float* ws = (float*)d_ws;
    float* t  = ws;                           // [B][2][HW] f32
    float* t2 = t + (size_t)B * 2 * HW;       // [B][2][HW] f32
    __hip_bfloat16* S = (__hip_bfloat16*)(t2 + (size_t)B * 2 * HW);  // [9][BHW] bf16
    float* gw = (float*)(S + (size_t)9 * BHW);                       // [64]
    float* wpack = gw + 64;                   // [LSTEPS*NPAIR][32]

    init_kernel<<<BHW / 256, 256, 0, stream>>>(source, z0, conv1_w, conv1_b, conv2_w,
                                               images, residuals, gw, wpack);

    for (int i = 0; i < LSTEPS; i++) {
        const float* img_i = images + (size_t)i * B * HW;
        const float* z_i   = residuals + (size_t)i * B * HW;
        float* fields_i    = fields + (size_t)i * B * HW * 2;

        grad_smap_kernel<<<BHW / 256, 256, 0, stream>>>(z_i, img_i,
                wpack + (size_t)i * NPAIR * 32, S,
                grads + (size_t)i * B * 2 * HW, t);
        vblur_kernel<<<B * 2 * (W / VBC) * (H / VRT), 256, 0, stream>>>(t, gw, t2);
        hblur_deform_kernel<<<B * H, 256, 0, stream>>>(t2, gw, fields_i,
                img_i, z_i, S,
                residuals + (size_t)(i + 1) * B * HW, images + (size_t)(i + 1) * B * HW);
    }
}

// Round 9
// 292.855 us; speedup vs baseline: 1.4674x; 1.2828x over previous
//
#include <hip/hip_runtime.h>
#include <hip/hip_bf16.h>
#include <math.h>

#define B 4
#define H 256
#define W 256
#define HW 65536
#define BHW (B * HW)
#define LSTEPS 10
#define NCH 100
#define KS 51
#define KR 25

typedef __fp16 h2 __attribute__((ext_vector_type(2)));
typedef __fp16 half8 __attribute__((ext_vector_type(8)));
typedef float f32x4 __attribute__((ext_vector_type(4)));
typedef unsigned u32x4v __attribute__((ext_vector_type(4)));
typedef unsigned u32x2v __attribute__((ext_vector_type(2)));

static __device__ __forceinline__ h2 pack_f16(float a, float b) {
#if __has_builtin(__builtin_amdgcn_cvt_pkrtz)
    return __builtin_amdgcn_cvt_pkrtz(a, b);
#else
    h2 r; r.x = (__fp16)a; r.y = (__fp16)b; return r;
#endif
}
static __device__ __forceinline__ unsigned packu(float a, float b) {
    return __builtin_bit_cast(unsigned, pack_f16(a, b));
}

// ---------------- init: images[0]/residuals[0], gauss weights, f16 MFMA weight packs
// A1[i][112 rows][16 dw]: row c: dw t = (w1z[t], w1i[t]) t=0..8; dw9 = (bias, 0); dw10..15 = 0.
// A2[i][16 rows][64 dw]: row q: dw cp = (v2[2cp][q], v2[2cp+1][q]), 0 outside c<100,q<9.
__global__ void init_kernel(const float* __restrict__ src, const float* __restrict__ z0,
                            const float* __restrict__ conv1_w, const float* __restrict__ conv1_b,
                            const float* __restrict__ conv2_w,
                            float* __restrict__ images0, float* __restrict__ res0,
                            float* __restrict__ gw, unsigned* __restrict__ a1,
                            unsigned* __restrict__ a2) {
    int tid = blockIdx.x * 256 + threadIdx.x;   // 0 .. BHW-1
    images0[tid] = src[tid];
    res0[tid] = z0[tid & (HW - 1)];
    if (tid == 0) {
        float e[KS];
        float s = 0.f;
        for (int k = 0; k < KS; k++) {
            float x = (float)(k - KR) / 6.0f;
            e[k] = expf(-0.5f * x * x);
            s += e[k];
        }
        for (int k = 0; k < KS; k++) gw[k] = e[k] / s;
    }
    if (tid < LSTEPS * 112) {
        int i = tid / 112, c = tid % 112;
        unsigned* dst = a1 + (size_t)tid * 16;
        if (c < NCH) {
            const float* wz = conv1_w + ((size_t)i * NCH + c) * 18;
            float bias = conv1_b[(size_t)i * NCH + c];
#pragma unroll
            for (int t = 0; t < 9; t++) dst[t] = packu(wz[t], wz[9 + t]);
            dst[9] = packu(bias, 0.f);
#pragma unroll
            for (int t = 10; t < 16; t++) dst[t] = 0u;
        } else {
#pragma unroll
            for (int t = 0; t < 16; t++) dst[t] = 0u;
        }
    }
    if (tid >= 4096 && tid < 4096 + LSTEPS * 16) {
        int r = tid - 4096;
        int i = r / 16, q = r % 16;
        unsigned* dst = a2 + (size_t)r * 64;
        for (int cp = 0; cp < 64; cp++) {
            int c0 = 2 * cp, c1 = 2 * cp + 1;
            float f0 = (q < 9 && c0 < NCH) ? conv2_w[((size_t)i * NCH + c0) * 9 + q] : 0.f;
            float f1 = (q < 9 && c1 < NCH) ? conv2_w[((size_t)i * NCH + c1) * 9 + q] : 0.f;
            dst[cp] = packu(f0, f1);
        }
    }
}

// ---------------- MFMA resblock: sobel + im2col(LDS) + GEMM1(16x16x32 f16) + leaky
// + GEMM2 (S-map), one block per (b,row), 4 waves, each wave owns fixed 16-px slots.
__global__ __launch_bounds__(256, 4) void mfma_smap_kernel(
        const float* __restrict__ z, const float* __restrict__ img,
        const unsigned* __restrict__ a1, const unsigned* __restrict__ a2,
        __hip_bfloat16* __restrict__ S,
        float* __restrict__ grads_i, float* __restrict__ t) {
    __shared__ unsigned feat_l[256 * 16];   // [px][16 dw] = 32 f16 features, XOR-swz (px&3)
    __shared__ unsigned h_l[64 * 64];       // [px-slot][64 dw] = 128 f16 ch, XOR-swz (px&15)
    int bid = blockIdx.x;
    int b = bid >> 8, y = bid & 255;
    int x = threadIdx.x;
    int p = y * W + x;
    const float* zp = z + (b << 16);
    const float* ip = img + (b << 16);

    // patch loads: ri = raw clamped img (Sobel), fd = zero-padded (z,img) f16 pairs
    float ri[9];
    unsigned fd[16];
    float zc = 0.f;
#pragma unroll
    for (int dy = -1; dy <= 1; dy++) {
#pragma unroll
        for (int dx = -1; dx <= 1; dx++) {
            int yy = y + dy, xx = x + dx;
            bool ok = ((unsigned)yy < (unsigned)H) && ((unsigned)xx < (unsigned)W);
            int yc = min(max(yy, 0), H - 1);
            int xc = min(max(xx, 0), W - 1);
            int k = (dy + 1) * 3 + (dx + 1);
            float vz = zp[yc * W + xc], vi = ip[yc * W + xc];
            ri[k] = vi;
            float az = ok ? vz : 0.f, ai = ok ? vi : 0.f;
            if (k == 4) zc = az;
            fd[k] = packu(az, ai);
        }
    }
    float gx = ((ri[2] + 2.f * ri[5] + ri[8]) - (ri[0] + 2.f * ri[3] + ri[6])) * 0.125f;
    float gy = ((ri[6] + 2.f * ri[7] + ri[8]) - (ri[0] + 2.f * ri[1] + ri[2])) * 0.125f;
    grads_i[(b * 2 + 0) * HW + p] = gx;
    grads_i[(b * 2 + 1) * HW + p] = gy;
    t[(b * 2 + 0) * HW + p] = -zc * gx;
    t[(b * 2 + 1) * HW + p] = -zc * gy;

    fd[9] = packu(1.0f, 0.f);                // bias feature (k=18) = 1.0, k=19 = 0
#pragma unroll
    for (int k = 10; k < 16; k++) fd[k] = 0u;

    {   // feat write (swizzled)
        unsigned base = (unsigned)(x * 16);
        unsigned swzf = (unsigned)((x & 3) << 2);
#pragma unroll
        for (int g = 0; g < 4; g++) {
            u32x4v v = {fd[g * 4], fd[g * 4 + 1], fd[g * 4 + 2], fd[g * 4 + 3]};
            *(u32x4v*)(feat_l + base + ((unsigned)(g * 4) ^ swzf)) = v;
        }
    }
    if (x < 64) {   // zero h ch 112..127 (A2 weight 0 there; avoid NaN*0)
        unsigned swz0 = (unsigned)((x & 15) << 2);
        u32x4v zv = {0u, 0u, 0u, 0u};
        *(u32x4v*)(h_l + x * 64 + (56u ^ swz0)) = zv;
        *(u32x4v*)(h_l + x * 64 + (60u ^ swz0)) = zv;
    }

    int w = threadIdx.x >> 6;
    int lane = threadIdx.x & 63;
    int l15 = lane & 15, lg = lane >> 4;

    half8 A1f[7];
#pragma unroll
    for (int mt = 0; mt < 7; mt++)
        A1f[mt] = __builtin_bit_cast(half8,
            *(const u32x4v*)(a1 + (size_t)((mt * 16 + l15) * 16 + lg * 4)));
    half8 A2f[4];
#pragma unroll
    for (int ks = 0; ks < 4; ks++)
        A2f[ks] = __builtin_bit_cast(half8,
            *(const u32x4v*)(a2 + (size_t)(l15 * 64 + ks * 16 + lg * 4)));

    __syncthreads();

    unsigned hrow = (unsigned)((w * 16 + l15) * 64);
    unsigned swz = (unsigned)(l15 << 2);
    unsigned fswz = (unsigned)((l15 & 3) << 2);

#pragma unroll
    for (int qt = 0; qt < 4; qt++) {
        int pxq = qt * 64 + w * 16;
        half8 B1f = __builtin_bit_cast(half8,
            *(const u32x4v*)(feat_l + (unsigned)((pxq + l15) * 16) + ((unsigned)(lg * 4) ^ fswz)));
        f32x4 zero4 = {0.f, 0.f, 0.f, 0.f};
        f32x4 acc[7];
#pragma unroll
        for (int mt = 0; mt < 7; mt++)
            acc[mt] = __builtin_amdgcn_mfma_f32_16x16x32_f16(A1f[mt], B1f, zero4, 0, 0, 0);
        // leaky + pack f16 + store hidden (own slots; intra-wave ordering via lgkmcnt)
#pragma unroll
        for (int mt = 0; mt < 7; mt++) {
            float l0 = fmaxf(acc[mt][0], 0.01f * acc[mt][0]);
            float l1 = fmaxf(acc[mt][1], 0.01f * acc[mt][1]);
            float l2 = fmaxf(acc[mt][2], 0.01f * acc[mt][2]);
            float l3 = fmaxf(acc[mt][3], 0.01f * acc[mt][3]);
            u32x2v dv = {packu(l0, l1), packu(l2, l3)};
            unsigned c = (unsigned)(mt * 8 + lg * 2);
            *(u32x2v*)(h_l + hrow + (c ^ swz)) = dv;
        }
        f32x4 acc2 = {0.f, 0.f, 0.f, 0.f};
#pragma unroll
        for (int ks = 0; ks < 4; ks++) {
            half8 B2f = __builtin_bit_cast(half8,
                *(const u32x4v*)(h_l + hrow + ((unsigned)(ks * 16 + lg * 4) ^ swz)));
            acc2 = __builtin_amdgcn_mfma_f32_16x16x32_f16(A2f[ks], B2f, acc2, 0, 0, 0);
        }
        int xg = pxq + l15;
        size_t sbase = (size_t)(b << 16) + (size_t)y * W + xg;
#pragma unroll
        for (int r = 0; r < 4; r++) {
            int q = lg * 4 + r;
            if (q < 9) S[(size_t)q * BHW + sbase] = __float2bfloat16(acc2[r]);
        }
    }
}

// ---------------- vertical 51-tap blur (zero pad), 2D tiled
#define VBC 32
#define VRT 32
__global__ void vblur_kernel(const float* __restrict__ t, const float* __restrict__ gw,
                             float* __restrict__ t2) {
    int bid = blockIdx.x;
    int rt = bid & 7;
    int ct = (bid >> 3) & 7;
    int bc = bid >> 6;
    int row0 = rt * VRT, col0 = ct * VBC;
    __shared__ float s[(VRT + 2 * KR) * VBC];
    const float* src = t + bc * HW + col0;
    for (int idx = threadIdx.x; idx < (VRT + 2 * KR) * VBC; idx += 256) {
        int r = idx >> 5, c = idx & 31;
        int row = row0 + r - KR;
        s[idx] = ((unsigned)row < (unsigned)H) ? src[row * W + c] : 0.f;
    }
    __syncthreads();
    int c = threadIdx.x & 31;
    int rbase = (threadIdx.x >> 5) * 4;
    float* dst = t2 + bc * HW + col0;
#pragma unroll
    for (int j = 0; j < 4; j++) {
        int row = rbase + j;
        float acc = 0.f;
#pragma unroll
        for (int k = 0; k < KS; k++) acc += gw[k] * s[(row + k) * VBC + c];
        dst[(row0 + row) * W + c] = acc;
    }
}

// ---------------- horizontal blur + fields + S-gather (conv2 finish) + deform
__global__ void hblur_deform_kernel(const float* __restrict__ t2, const float* __restrict__ gw,
                                    float* __restrict__ fields_i,
                                    const float* __restrict__ img, const float* __restrict__ z,
                                    const __hip_bfloat16* __restrict__ S,
                                    float* __restrict__ res_next, float* __restrict__ img_next) {
    int b = blockIdx.x >> 8;
    int row = blockIdx.x & 255;
    __shared__ float s0[W + 2 * KR], s1[W + 2 * KR];
    const float* r0 = t2 + (b * 2 + 0) * HW + row * W;
    const float* r1 = t2 + (b * 2 + 1) * HW + row * W;
    for (int idx = threadIdx.x; idx < W + 2 * KR; idx += 256) {
        int xx = idx - KR;
        bool ok = (xx >= 0 && xx < W);
        s0[idx] = ok ? r0[xx] : 0.f;
        s1[idx] = ok ? r1[xx] : 0.f;
    }
    __syncthreads();
    int x = threadIdx.x;
    float a0 = 0.f, a1v = 0.f;
#pragma unroll
    for (int k = 0; k < KS; k++) {
        float wk = gw[k];
        a0 += wk * s0[x + k];
        a1v += wk * s1[x + k];
    }
    int p = row * W + x;
    int tid = (b << 16) + p;
    float2* fdst = (float2*)(fields_i + (size_t)tid * 2);
    *fdst = make_float2(a0, a1v);

    float f = 0.f;
#pragma unroll
    for (int q = 0; q < 9; q++) {
        int yy = row - 1 + q / 3;
        int xx = x - 1 + q % 3;
        if (((unsigned)yy < (unsigned)H) && ((unsigned)xx < (unsigned)W))
            f += __bfloat162float(S[(size_t)q * BHW + (b << 16) + yy * W + xx]);
    }
    float zn = z[tid] + f / 10.0f;
    res_next[tid] = zn;

    float sx = (float)x - a0 / 10.0f;
    float sy = (float)row - a1v / 10.0f;
    float x0f = floorf(sx), y0f = floorf(sy);
    float wx = sx - x0f, wy = sy - y0f;
    int ix0 = min(max((int)x0f, 0), W - 1);
    int ix1 = min(max((int)x0f + 1, 0), W - 1);
    int iy0 = min(max((int)y0f, 0), H - 1);
    int iy1 = min(max((int)y0f + 1, 0), H - 1);
    const float* im = img + (b << 16);
    float Ia = im[iy0 * W + ix0], Ib = im[iy0 * W + ix1];
    float Ic = im[iy1 * W + ix0], Id = im[iy1 * W + ix1];
    float out = (1.f - wx) * (1.f - wy) * Ia + wx * (1.f - wy) * Ib
              + (1.f - wx) * wy * Ic + wx * wy * Id;
    img_next[tid] = out + zn * 0.001f;
}

extern "C" void kernel_launch(void* const* d_in, const int* in_sizes, int n_in,
                              void* d_out, int out_size, void* d_ws, size_t ws_size,
                              hipStream_t stream) {
    const float* source  = (const float*)d_in[0];
    const float* z0      = (const float*)d_in[1];
    const float* conv1_w = (const float*)d_in[2];
    const float* conv1_b = (const float*)d_in[3];
    const float* conv2_w = (const float*)d_in[4];

    float* out = (float*)d_out;
    float* images    = out;                              // [11][B][HW]
    float* fields    = images + (size_t)11 * B * HW;     // [10][B][HW][2]
    float* residuals = fields + (size_t)10 * B * HW * 2; // [11][B][HW]
    float* grads     = residuals + (size_t)11 * B * HW;  // [10][B][2][HW]

    float* ws = (float*)d_ws;
    float* t  = ws;                           // [B][2][HW] f32
    float* t2 = t + (size_t)B * 2 * HW;       // [B][2][HW] f32
    __hip_bfloat16* S = (__hip_bfloat16*)(t2 + (size_t)B * 2 * HW);  // [9][BHW] bf16
    float* gw = (float*)(S + (size_t)9 * BHW);                       // [64]
    unsigned* a1 = (unsigned*)(gw + 64);      // [10][112][16] dw
    unsigned* a2 = a1 + (size_t)LSTEPS * 112 * 16;  // [10][16][64] dw

    init_kernel<<<BHW / 256, 256, 0, stream>>>(source, z0, conv1_w, conv1_b, conv2_w,
                                               images, residuals, gw, a1, a2);

    for (int i = 0; i < LSTEPS; i++) {
        const float* img_i = images + (size_t)i * B * HW;
        const float* z_i   = residuals + (size_t)i * B * HW;
        float* fields_i    = fields + (size_t)i * B * HW * 2;

        mfma_smap_kernel<<<B * H, 256, 0, stream>>>(z_i, img_i,
                a1 + (size_t)i * 112 * 16, a2 + (size_t)i * 16 * 64, S,
                grads + (size_t)i * B * 2 * HW, t);
        vblur_kernel<<<B * 2 * (W / VBC) * (H / VRT), 256, 0, stream>>>(t, gw, t2);
        hblur_deform_kernel<<<B * H, 256, 0, stream>>>(t2, gw, fields_i,
                img_i, z_i, S,
                residuals + (size_t)(i + 1) * B * HW, images + (size_t)(i + 1) * B * HW);
    }
}